// Round 3
// baseline (633.387 us; speedup 1.0000x reference)
//
#include <hip/hip_runtime.h>

#define NTAGS 128
#define BB    256
#define SS    512

typedef float f32x2 __attribute__((ext_vector_type(2)));

__global__ void zero_out_kernel(float* out) { out[0] = 0.0f; }

__global__ __launch_bounds__(64, 1) void crf_fwd_kernel(
    const float* __restrict__ emissions,        // [B, S, NTAGS] f32
    const int* __restrict__ tags,               // [B, S] int32
    const unsigned char* __restrict__ mask,     // [B, S] bool
    const float* __restrict__ trans,            // [NTAGS, NTAGS] f32
    float* __restrict__ out)                    // [1] f32
{
    const int b = blockIdx.x;
    const int l = threadIdx.x;                  // 0..63; owns cols l and l+64

    __shared__ __align__(16) float p_sh[NTAGS];
    __shared__ int   tags_sh[SS];
    __shared__ float mask_sh[SS];

    // ---- stage tags / mask (single wave; ordering via lgkmcnt) ----
    for (int t = l; t < SS; t += 64) {
        tags_sh[t] = tags[b * SS + t];
        mask_sh[t] = mask[b * SS + t] ? 1.0f : 0.0f;
    }

    // ---- expT columns l and l+64 in registers (i packed in pairs) ----
    f32x2 eTA[64], eTB[64];
    #pragma unroll
    for (int k = 0; k < 64; k++) {
        f32x2 va, vb;
        va.x = __expf(trans[(2 * k + 0) * NTAGS + l]);
        va.y = __expf(trans[(2 * k + 1) * NTAGS + l]);
        vb.x = __expf(trans[(2 * k + 0) * NTAGS + l + 64]);
        vb.y = __expf(trans[(2 * k + 1) * NTAGS + l + 64]);
        eTA[k] = va; eTB[k] = vb;
    }
    __syncthreads();   // one-time; staging done

    // ---- gold transition score (parallel over lanes) ----
    float gold = 0.0f;
    for (int t = 1 + l; t < SS; t += 64)
        gold += trans[tags_sh[t - 1] * NTAGS + tags_sh[t]] * mask_sh[t];

    const float* emB = emissions + (size_t)b * SS * NTAGS;
    float alphaA = emB[l];
    float alphaB = emB[l + 64];
    {
        int t0 = tags_sh[0];
        if (t0 == l)      gold += alphaA * mask_sh[0];
        if (t0 == l + 64) gold += alphaB * mask_sh[0];
    }

    // ---- initial wave max of alpha0 ----
    float M;
    {
        float v = fmaxf(alphaA, alphaB);
        #pragma unroll
        for (int o = 32; o > 0; o >>= 1) v = fmaxf(v, __shfl_xor(v, o));
        M = v;
    }

    // ---- emission register pipeline (depth 2) ----
    float eA0 = emB[1 * NTAGS + l],      eB0 = emB[1 * NTAGS + l + 64];   // t=1
    float eA1 = emB[2 * NTAGS + l],      eB1 = emB[2 * NTAGS + l + 64];   // t=2

    // ---- forward recursion: NO barriers ----
    for (int t = 1; t < SS; t += 2) {
        // ======== step t ========
        {
            float pA = __expf(alphaA - M);
            float pB = __expf(alphaB - M);
            p_sh[l] = pA;
            p_sh[l + 64] = pB;
            // stale max for step t+1 (off critical chain)
            float v = fmaxf(alphaA, alphaB);
            #pragma unroll
            for (int o = 32; o > 0; o >>= 1) v = fmaxf(v, __shfl_xor(v, o));
            float Mn = v;

            const float4* p4 = (const float4*)p_sh;
            f32x2 a0 = {0.f,0.f}, a1 = {0.f,0.f}, b0 = {0.f,0.f}, b1 = {0.f,0.f};
            #pragma unroll
            for (int k = 0; k < 32; k++) {
                float4 pv = p4[k];
                f32x2 lo = {pv.x, pv.y}, hi = {pv.z, pv.w};
                a0 = __builtin_elementwise_fma(lo, eTA[2 * k + 0], a0);
                a1 = __builtin_elementwise_fma(hi, eTA[2 * k + 1], a1);
                b0 = __builtin_elementwise_fma(lo, eTB[2 * k + 0], b0);
                b1 = __builtin_elementwise_fma(hi, eTB[2 * k + 1], b1);
            }
            float sA = (a0.x + a0.y) + (a1.x + a1.y);
            float sB = (b0.x + b0.y) + (b1.x + b1.y);

            float etA = eA0, etB = eB0;
            int tn = t + 2; if (tn > SS - 1) tn = SS - 1;
            eA0 = emB[(size_t)tn * NTAGS + l];
            eB0 = emB[(size_t)tn * NTAGS + l + 64];

            alphaA = M + __logf(sA) + etA;
            alphaB = M + __logf(sB) + etB;
            int tg = tags_sh[t];
            if (tg == l)      gold += etA * mask_sh[t];
            if (tg == l + 64) gold += etB * mask_sh[t];
            M = Mn;
        }
        // ======== step t+1 ========
        if (t + 1 < SS) {
            float pA = __expf(alphaA - M);
            float pB = __expf(alphaB - M);
            p_sh[l] = pA;
            p_sh[l + 64] = pB;
            float v = fmaxf(alphaA, alphaB);
            #pragma unroll
            for (int o = 32; o > 0; o >>= 1) v = fmaxf(v, __shfl_xor(v, o));
            float Mn = v;

            const float4* p4 = (const float4*)p_sh;
            f32x2 a0 = {0.f,0.f}, a1 = {0.f,0.f}, b0 = {0.f,0.f}, b1 = {0.f,0.f};
            #pragma unroll
            for (int k = 0; k < 32; k++) {
                float4 pv = p4[k];
                f32x2 lo = {pv.x, pv.y}, hi = {pv.z, pv.w};
                a0 = __builtin_elementwise_fma(lo, eTA[2 * k + 0], a0);
                a1 = __builtin_elementwise_fma(hi, eTA[2 * k + 1], a1);
                b0 = __builtin_elementwise_fma(lo, eTB[2 * k + 0], b0);
                b1 = __builtin_elementwise_fma(hi, eTB[2 * k + 1], b1);
            }
            float sA = (a0.x + a0.y) + (a1.x + a1.y);
            float sB = (b0.x + b0.y) + (b1.x + b1.y);

            float etA = eA1, etB = eB1;
            int tn = t + 3; if (tn > SS - 1) tn = SS - 1;
            eA1 = emB[(size_t)tn * NTAGS + l];
            eB1 = emB[(size_t)tn * NTAGS + l + 64];

            alphaA = M + __logf(sA) + etA;
            alphaB = M + __logf(sB) + etB;
            int tg = tags_sh[t + 1];
            if (tg == l)      gold += etA * mask_sh[t + 1];
            if (tg == l + 64) gold += etB * mask_sh[t + 1];
            M = Mn;
        }
    }

    // ---- epilogue: logsumexp over 128 alphas + gold reduce (in-wave) ----
    {
        float g = gold;
        #pragma unroll
        for (int o = 32; o > 0; o >>= 1) g += __shfl_xor(g, o);

        float mm = fmaxf(alphaA, alphaB);
        #pragma unroll
        for (int o = 32; o > 0; o >>= 1) mm = fmaxf(mm, __shfl_xor(mm, o));

        float ev = __expf(alphaA - mm) + __expf(alphaB - mm);
        #pragma unroll
        for (int o = 32; o > 0; o >>= 1) ev += __shfl_xor(ev, o);

        if (l == 0) atomicAdd(out, mm + __logf(ev) - g);
    }
}

extern "C" void kernel_launch(void* const* d_in, const int* in_sizes, int n_in,
                              void* d_out, int out_size, void* d_ws, size_t ws_size,
                              hipStream_t stream) {
    const float*         emissions = (const float*)d_in[0];
    const int*           tags      = (const int*)d_in[1];
    const unsigned char* mask      = (const unsigned char*)d_in[2];
    const float*         trans     = (const float*)d_in[3];
    float*               out       = (float*)d_out;

    zero_out_kernel<<<1, 1, 0, stream>>>(out);
    crf_fwd_kernel<<<BB, 64, 0, stream>>>(emissions, tags, mask, trans, out);
}

// Round 4
// 426.614 us; speedup vs baseline: 1.4847x; 1.4847x over previous
//
#include <hip/hip_runtime.h>

#define NTAGS 128
#define BB    256
#define SS    512

typedef float f32x2 __attribute__((ext_vector_type(2)));

__device__ __forceinline__ float rdlane(float v, int lane) {
    return __int_as_float(__builtin_amdgcn_readlane(__float_as_int(v), lane));
}

__global__ void zero_out_kernel(float* out) { out[0] = 0.0f; }

__global__ __launch_bounds__(128, 1) void crf_fwd_kernel(
    const float* __restrict__ emissions,        // [B, S, NTAGS] f32
    const int* __restrict__ tags,               // [B, S] int32
    const unsigned char* __restrict__ mask,     // [B, S] bool
    const float* __restrict__ trans,            // [NTAGS, NTAGS] f32
    float* __restrict__ out)                    // [1] f32
{
    const int b   = blockIdx.x;
    const int tid = threadIdx.x;                // 0..127
    const int l   = tid & 63;                   // lane
    const int w   = tid >> 6;                   // wave 0/1
    const int jO  = (w << 6) + l;               // owned row & column
    const int jX  = ((1 - w) << 6) + l;         // column owned by other wave

    __shared__ __align__(16) float pbuf[2][NTAGS];   // parity partial exchange
    __shared__ float Mbuf[2][2];                     // parity wave-max exchange
    __shared__ int   tags_sh[SS];
    __shared__ float mask_sh[SS];
    __shared__ float red_sh[8];

    // ---- stage tags / mask ----
    for (int t = tid; t < SS; t += 128) {
        tags_sh[t] = tags[b * SS + t];
        mask_sh[t] = mask[b * SS + t] ? 1.0f : 0.0f;
    }

    // ---- expT: own 64 rows (i = 64w + 2k, 2k+1), columns jO and jX ----
    f32x2 eTO[32], eTX[32];
    #pragma unroll
    for (int k = 0; k < 32; k++) {
        const float* r0 = trans + (size_t)((w << 6) + 2 * k) * NTAGS;
        f32x2 vo, vx;
        vo.x = __expf(r0[jO]);         vo.y = __expf(r0[NTAGS + jO]);
        vx.x = __expf(r0[jX]);         vx.y = __expf(r0[NTAGS + jX]);
        eTO[k] = vo; eTX[k] = vx;
    }

    __syncthreads();   // tags_sh / mask_sh ready

    // ---- gold transition score ----
    float gold = 0.0f;
    for (int t = 1 + tid; t < SS; t += 128)
        gold += trans[tags_sh[t - 1] * NTAGS + tags_sh[t]] * mask_sh[t];

    const float* emB = emissions + (size_t)b * SS * NTAGS;
    float alpha = emB[jO];
    if (tags_sh[0] == jO) gold += alpha * mask_sh[0];

    // ---- initial per-wave max, exchanged for step 1 (parity 1) ----
    float M;
    {
        float v = alpha;
        #pragma unroll
        for (int o = 32; o > 0; o >>= 1) v = fmaxf(v, __shfl_xor(v, o));
        M = v;
    }
    if (l == 0) Mbuf[1][w] = M;

    // ---- emission prefetch pipeline (depth 2), 1 value/lane/step ----
    float eO = emB[(size_t)1 * NTAGS + jO];   // for t=1
    float eE = emB[(size_t)2 * NTAGS + jO];   // for t=2

    __syncthreads();
    float Mo = Mbuf[1][1 - w];                // other wave's M for step 1

    // ---- forward recursion: 1 barrier/step, no LDS p-broadcast ----
    for (int t = 1; t < SS; t += 2) {
        // ======== odd step t (parity 1) ========
        {
            float m  = fmaxf(M, Mo);          // off-chain: known at step start
            float fO = __expf(M  - m);
            float fX = __expf(Mo - m);
            float p  = __expf(alpha - M);

            // stale per-wave max for step t+1 (off critical chain)
            float v = alpha;
            #pragma unroll
            for (int o = 32; o > 0; o >>= 1) v = fmaxf(v, __shfl_xor(v, o));
            float Mn = v;

            f32x2 accO = {0.f, 0.f}, accX = {0.f, 0.f};
            #pragma unroll
            for (int k = 0; k < 32; k++) {
                f32x2 pv;
                pv.x = rdlane(p, 2 * k);
                pv.y = rdlane(p, 2 * k + 1);
                accO = __builtin_elementwise_fma(pv, eTO[k], accO);
                accX = __builtin_elementwise_fma(pv, eTX[k], accX);
            }
            float sO = accO.x + accO.y;
            float sX = accX.x + accX.y;

            pbuf[1][jX] = sX;                 // give other wave its partial
            if (l == 0) Mbuf[0][w] = Mn;      // M for step t+1 (parity 0)
            __syncthreads();
            float oP = pbuf[1][jO];
            float oM = Mbuf[0][1 - w];

            float e_t = eO;
            int tn = t + 2; if (tn > SS - 1) tn = SS - 1;
            eO = emB[(size_t)tn * NTAGS + jO];

            alpha = m + __logf(fmaf(fO, sO, fX * oP)) + e_t;
            if (tags_sh[t] == jO) gold += e_t * mask_sh[t];
            M = Mn; Mo = oM;
        }
        // ======== even step t+1 (parity 0) ========
        if (t + 1 < SS) {
            float m  = fmaxf(M, Mo);
            float fO = __expf(M  - m);
            float fX = __expf(Mo - m);
            float p  = __expf(alpha - M);

            float v = alpha;
            #pragma unroll
            for (int o = 32; o > 0; o >>= 1) v = fmaxf(v, __shfl_xor(v, o));
            float Mn = v;

            f32x2 accO = {0.f, 0.f}, accX = {0.f, 0.f};
            #pragma unroll
            for (int k = 0; k < 32; k++) {
                f32x2 pv;
                pv.x = rdlane(p, 2 * k);
                pv.y = rdlane(p, 2 * k + 1);
                accO = __builtin_elementwise_fma(pv, eTO[k], accO);
                accX = __builtin_elementwise_fma(pv, eTX[k], accX);
            }
            float sO = accO.x + accO.y;
            float sX = accX.x + accX.y;

            pbuf[0][jX] = sX;
            if (l == 0) Mbuf[1][w] = Mn;      // M for step t+2 (parity 1)
            __syncthreads();
            float oP = pbuf[0][jO];
            float oM = Mbuf[1][1 - w];

            float e_t = eE;
            int tn = t + 3; if (tn > SS - 1) tn = SS - 1;
            eE = emB[(size_t)tn * NTAGS + jO];

            alpha = m + __logf(fmaf(fO, sO, fX * oP)) + e_t;
            if (tags_sh[t + 1] == jO) gold += e_t * mask_sh[t + 1];
            M = Mn; Mo = oM;
        }
    }

    // ---- epilogue: logsumexp over 128 alphas + gold reduction ----
    {
        float g = gold;
        #pragma unroll
        for (int o = 32; o > 0; o >>= 1) g += __shfl_xor(g, o);

        float mW = alpha;
        #pragma unroll
        for (int o = 32; o > 0; o >>= 1) mW = fmaxf(mW, __shfl_xor(mW, o));

        float ev = __expf(alpha - mW);
        #pragma unroll
        for (int o = 32; o > 0; o >>= 1) ev += __shfl_xor(ev, o);

        if (l == 0) {
            red_sh[w]     = mW;
            red_sh[2 + w] = ev;
            red_sh[4 + w] = g;
        }
    }
    __syncthreads();
    if (tid == 0) {
        float m0 = red_sh[0], m1 = red_sh[1];
        float mm = fmaxf(m0, m1);
        float tot = __expf(m0 - mm) * red_sh[2] + __expf(m1 - mm) * red_sh[3];
        float part = mm + __logf(tot);
        float gtot = red_sh[4] + red_sh[5];
        atomicAdd(out, part - gtot);
    }
}

extern "C" void kernel_launch(void* const* d_in, const int* in_sizes, int n_in,
                              void* d_out, int out_size, void* d_ws, size_t ws_size,
                              hipStream_t stream) {
    const float*         emissions = (const float*)d_in[0];
    const int*           tags      = (const int*)d_in[1];
    const unsigned char* mask      = (const unsigned char*)d_in[2];
    const float*         trans     = (const float*)d_in[3];
    float*               out       = (float*)d_out;

    zero_out_kernel<<<1, 1, 0, stream>>>(out);
    crf_fwd_kernel<<<BB, 128, 0, stream>>>(emissions, tags, mask, trans, out);
}

// Round 5
// 416.789 us; speedup vs baseline: 1.5197x; 1.0236x over previous
//
#include <hip/hip_runtime.h>

#define NTAGS 128
#define BB    256
#define SS    512

typedef float f32x2 __attribute__((ext_vector_type(2)));

// barrier that drains only LDS (lgkm) — global prefetches stay in flight
__device__ __forceinline__ void lds_barrier() {
    asm volatile("s_waitcnt lgkmcnt(0)\n\ts_barrier" ::: "memory");
}

__device__ __forceinline__ int fexp_of(float x) {   // exponent of positive normal f32
    return (int)((__float_as_uint(x) >> 23) & 0xFFu) - 127;
}

__global__ void zero_out_kernel(float* out) { out[0] = 0.0f; }

__global__ __launch_bounds__(128, 1) void crf_fwd_kernel(
    const float* __restrict__ emissions,        // [B, S, NTAGS] f32
    const int* __restrict__ tags,               // [B, S] int32
    const unsigned char* __restrict__ mask,     // [B, S] bool
    const float* __restrict__ trans,            // [NTAGS, NTAGS] f32
    float* __restrict__ out)                    // [1] f32
{
    const int b = blockIdx.x;
    const int j = threadIdx.x;                  // 0..127 — owns column j
    const int l = j & 63;
    const int w = j >> 6;                       // wave 0/1 (rows 64w..64w+63)

    __shared__ __align__(16) float p_sh[2][NTAGS];   // parity p exchange
    __shared__ int   sbuf[2][2];                     // parity per-wave S (exact)
    __shared__ int   tags_sh[SS];
    __shared__ float mask_sh[SS];
    __shared__ float redf[8];
    __shared__ int   redi[4];

    // ---- stage tags / mask ----
    for (int t = j; t < SS; t += 128) {
        tags_sh[t] = tags[b * SS + t];
        mask_sh[t] = mask[b * SS + t] ? 1.0f : 0.0f;
    }

    // ---- expT column j in registers (row pairs) ----
    f32x2 eT2[64];
    #pragma unroll
    for (int k = 0; k < 64; k++) {
        f32x2 v;
        v.x = __expf(trans[(2 * k + 0) * NTAGS + j]);
        v.y = __expf(trans[(2 * k + 1) * NTAGS + j]);
        eT2[k] = v;
    }
    __syncthreads();

    // ---- gold transition score ----
    float gold = 0.0f;
    for (int t = 1 + j; t < SS; t += 128)
        gold += trans[tags_sh[t - 1] * NTAGS + tags_sh[t]] * mask_sh[t];

    const float* emB = emissions + (size_t)b * SS * NTAGS;
    float a0v = emB[j];
    if (tags_sh[0] == j) gold += a0v * mask_sh[0];

    // ---- one-time block max M0 (float offset, added at the end) ----
    float M0;
    {
        float v = a0v;
        #pragma unroll
        for (int o = 32; o > 0; o >>= 1) v = fmaxf(v, __shfl_xor(v, o));
        if (l == 0) redf[w] = v;
        __syncthreads();
        M0 = fmaxf(redf[0], redf[1]);
    }

    // ---- exp-space state: true alpha_j = pj * 2^S_own * e^M0 ----
    float pj = __expf(a0v - M0);
    int S_own = 0;
    int exn_prev = fexp_of(pj);
    int K;
    {
        int kv = exn_prev;
        #pragma unroll
        for (int o = 32; o > 0; o >>= 1) kv = max(kv, __shfl_xor(kv, o));
        K = kv;
    }

    // ---- emission pipeline: raw e_t 2 steps deep per parity; exp off-chain ----
    float rawO = emB[(size_t)1 * NTAGS + j];
    float rawE = emB[(size_t)2 * NTAGS + j];
    float infO = emB[(size_t)3 * NTAGS + j];
    float infE = emB[(size_t)4 * NTAGS + j];
    float exO = __expf(rawO);                   // exp(e_1)
    float exE = __expf(rawE);                   // exp(e_2)

    auto step = [&](int t, int q, float& raw_cur, float& raw_inf, float& ex_cur) {
        p_sh[q][j] = pj;
        if (l == 0) sbuf[q][w] = S_own;
        lds_barrier();                           // lgkm-only drain
        int S_oth = sbuf[q][1 - w];

        // off-chain: next rescale exponent from 1-step-stale pj exponents
        int kv = exn_prev;
        #pragma unroll
        for (int o = 32; o > 0; o >>= 1) kv = max(kv, __shfl_xor(kv, o));

        const float4* p4 = (const float4*)(p_sh[q]);
        f32x2 aL0 = {0.f,0.f}, aL1 = {0.f,0.f};  // rows 0..63  (wave 0's scale)
        f32x2 aH0 = {0.f,0.f}, aH1 = {0.f,0.f};  // rows 64..127 (wave 1's scale)
        #pragma unroll
        for (int c = 0; c < 16; c++) {
            float4 pv = p4[c];
            f32x2 lo = {pv.x, pv.y}, hi = {pv.z, pv.w};
            aL0 = __builtin_elementwise_fma(lo, eT2[2 * c + 0], aL0);
            aL1 = __builtin_elementwise_fma(hi, eT2[2 * c + 1], aL1);
        }
        #pragma unroll
        for (int c = 16; c < 32; c++) {
            float4 pv = p4[c];
            f32x2 lo = {pv.x, pv.y}, hi = {pv.z, pv.w};
            aH0 = __builtin_elementwise_fma(lo, eT2[2 * c + 0], aH0);
            aH1 = __builtin_elementwise_fma(hi, eT2[2 * c + 1], aH1);
        }
        float sLow  = (aL0.x + aL0.y) + (aL1.x + aL1.y);
        float sHigh = (aH0.x + aH0.y) + (aH1.x + aH1.y);
        float sOwn = w ? sHigh : sLow;
        float sOth = w ? sLow  : sHigh;

        float s  = sOwn + ldexpf(sOth, S_oth - S_own);   // exact scale combine
        float sn = s * ex_cur;                            // * exp(e_t), precomputed

        if (tags_sh[t] == j) gold += raw_cur * mask_sh[t];

        pj = ldexpf(sn, -K);                    // exact power-of-2 rescale
        S_own += K;
        exn_prev = fexp_of(sn) - K;             // exponent of new pj
        K = kv;

        // rotate emission pipeline (load for t+4; exp for t+2 — off-chain)
        float nr = raw_inf;
        int tn = t + 4; if (tn > SS - 1) tn = SS - 1;
        raw_inf = emB[(size_t)tn * NTAGS + j];
        raw_cur = nr;
        ex_cur  = __expf(nr);
    };

    for (int t = 1; t < SS; t += 2) {
        step(t, 1, rawO, infO, exO);
        if (t + 1 < SS) step(t + 1, 0, rawE, infE, exE);
    }

    // ---- epilogue: partition = M0 + S*ln2 + log(sum p̂), reduce gold ----
    {
        float g = gold;
        #pragma unroll
        for (int o = 32; o > 0; o >>= 1) g += __shfl_xor(g, o);
        float sw = pj;
        #pragma unroll
        for (int o = 32; o > 0; o >>= 1) sw += __shfl_xor(sw, o);
        if (l == 0) { redf[w] = sw; redf[2 + w] = g; redi[w] = S_own; }
    }
    __syncthreads();
    if (j == 0) {
        int SA = redi[0], SB = redi[1];
        int Sm = (SA > SB) ? SA : SB;
        float tot = ldexpf(redf[0], SA - Sm) + ldexpf(redf[1], SB - Sm);
        float part = __logf(tot) + (float)Sm * 0.69314718055994531f + M0;
        atomicAdd(out, part - (redf[2] + redf[3]));
    }
}

extern "C" void kernel_launch(void* const* d_in, const int* in_sizes, int n_in,
                              void* d_out, int out_size, void* d_ws, size_t ws_size,
                              hipStream_t stream) {
    const float*         emissions = (const float*)d_in[0];
    const int*           tags      = (const int*)d_in[1];
    const unsigned char* mask      = (const unsigned char*)d_in[2];
    const float*         trans     = (const float*)d_in[3];
    float*               out       = (float*)d_out;

    zero_out_kernel<<<1, 1, 0, stream>>>(out);
    crf_fwd_kernel<<<BB, 128, 0, stream>>>(emissions, tags, mask, trans, out);
}